// Round 4
// baseline (205.039 us; speedup 1.0000x reference)
//
#include <hip/hip_runtime.h>
#include <hip/hip_bf16.h>
#include <stdint.h>
#include <stddef.h>

// B=2, S=2048, D=1024, H=16, C=64
typedef __bf16 bf16;
typedef __bf16 bf16x8 __attribute__((ext_vector_type(8)));
typedef float f32x4 __attribute__((ext_vector_type(4)));

#define DEV __device__ __forceinline__

// async global->LDS, 16B per lane; LDS dest is wave-uniform base + lane*16
// (global side is per-lane addressed)
DEV void async16(const bf16* g, bf16* l) {
    __builtin_amdgcn_global_load_lds(
        (const __attribute__((address_space(1))) void*)g,
        (__attribute__((address_space(3))) void*)l,
        16, 0, 0);
}

// ---------------- conversions ----------------

__global__ void convert_x(const float* __restrict__ in, bf16* __restrict__ out, int n) {
    int i = (blockIdx.x * blockDim.x + threadIdx.x) * 4;
    if (i >= n) return;
    const float4 v = *(const float4*)(in + i);
    bf16 o4[4] = {(bf16)v.x, (bf16)v.y, (bf16)v.z, (bf16)v.w};
    *(uint2*)(out + i) = *(const uint2*)o4;
}

// all four 1024x1024 weight transposes in one launch (z = which weight)
__global__ void transpose_cvt_all(const float* __restrict__ Wq, const float* __restrict__ Wk,
                                  const float* __restrict__ Wv, const float* __restrict__ Wo,
                                  bf16* __restrict__ WqkvT, bf16* __restrict__ WoT) {
    const float* src;
    bf16* dst;
    float scale = 1.0f;
    switch (blockIdx.z) {
        case 0: src = Wq; dst = WqkvT; scale = 0.125f * 1.4426950408889634f; break;
        case 1: src = Wk; dst = WqkvT + 1024 * 1024; break;
        case 2: src = Wv; dst = WqkvT + 2 * 1024 * 1024; break;
        default: src = Wo; dst = WoT; break;
    }
    __shared__ float t[32][33];
    const int c0 = blockIdx.x * 32, r0 = blockIdx.y * 32;
    const int tx = threadIdx.x & 31, ty = threadIdx.x >> 5;  // 32x8
#pragma unroll
    for (int i = 0; i < 32; i += 8)
        t[ty + i][tx] = src[(size_t)(r0 + ty + i) * 1024 + c0 + tx];
    __syncthreads();
#pragma unroll
    for (int i = 0; i < 32; i += 8)
        dst[(size_t)(c0 + ty + i) * 1024 + r0 + tx] = (bf16)(t[tx][ty + i] * scale);
}

// V slice of QKV [4096][3072] (cols 2048..3071) -> VT [1024][4096]
__global__ void transpose_v(const bf16* __restrict__ V, bf16* __restrict__ VT) {
    __shared__ bf16 t[32][33];
    const int c0 = blockIdx.x * 32, r0 = blockIdx.y * 32;
    const int tx = threadIdx.x & 31, ty = threadIdx.x >> 5;  // 32x8
#pragma unroll
    for (int i = 0; i < 32; i += 8)
        t[ty + i][tx] = V[(size_t)(r0 + ty + i) * 3072 + c0 + tx];
    __syncthreads();
#pragma unroll
    for (int i = 0; i < 32; i += 8)
        VT[(size_t)(c0 + ty + i) * 4096 + r0 + tx] = t[tx][ty + i];
}

// ---------------- GEMM: C[m][n] = sum_k A[m][k] * BT[n][k] ----------------
// 128x128 tile, BK=64 staged as TWO BK=32 panels (keeps the bank-balanced
// 64 B row stride; one barrier pair per 64 K instead of per 32).
// 256 threads (4 waves in 2x2). M,N mult of 128; K mult of 64.

template <bool OUT_F32>
__global__ __launch_bounds__(256, 3) void gemm_bt(
    const bf16* __restrict__ A, const bf16* __restrict__ BT, void* __restrict__ Cout,
    int M, int N, int K) {
    __shared__ __attribute__((aligned(16))) bf16 As[2 * 128 * 32];
    __shared__ __attribute__((aligned(16))) bf16 Bs[2 * 128 * 32];
    const int tid = threadIdx.x;
    const int wid = tid >> 6;
    const int lane = tid & 63;
    const int quad = lane >> 4;
    const int l16 = lane & 15;
    const int wm = wid >> 1, wn = wid & 1;
    const int m0 = blockIdx.y * 128, n0 = blockIdx.x * 128;

    const int srow = wid * 32 + (lane >> 2);
    const int skcol = (lane & 3) * 8;
    const bf16* ag = A + (size_t)(m0 + srow) * K + skcol;
    const bf16* bg = BT + (size_t)(n0 + srow) * K + skcol;

    f32x4 acc[4][4];
#pragma unroll
    for (int i = 0; i < 4; ++i)
#pragma unroll
        for (int j = 0; j < 4; ++j) acc[i][j] = (f32x4){0.f, 0.f, 0.f, 0.f};

    for (int k0 = 0; k0 < K; k0 += 64) {
#pragma unroll
        for (int p = 0; p < 2; ++p) {
            async16(ag + k0 + p * 32, &As[p * 4096 + (wid * 32) * 32]);
            async16(ag + (size_t)16 * K + k0 + p * 32, &As[p * 4096 + (wid * 32 + 16) * 32]);
            async16(bg + k0 + p * 32, &Bs[p * 4096 + (wid * 32) * 32]);
            async16(bg + (size_t)16 * K + k0 + p * 32, &Bs[p * 4096 + (wid * 32 + 16) * 32]);
        }
        __syncthreads();

#pragma unroll
        for (int ks = 0; ks < 2; ++ks) {
            bf16x8 af[4], bfr[4];
#pragma unroll
            for (int mi = 0; mi < 4; ++mi)
                af[mi] = *(const bf16x8*)&As[ks * 4096 + (wm * 64 + mi * 16 + l16) * 32 + quad * 8];
#pragma unroll
            for (int ni = 0; ni < 4; ++ni)
                bfr[ni] = *(const bf16x8*)&Bs[ks * 4096 + (wn * 64 + ni * 16 + l16) * 32 + quad * 8];
#pragma unroll
            for (int mi = 0; mi < 4; ++mi)
#pragma unroll
                for (int ni = 0; ni < 4; ++ni)
                    acc[mi][ni] = __builtin_amdgcn_mfma_f32_16x16x32_bf16(
                        af[mi], bfr[ni], acc[mi][ni], 0, 0, 0);
        }
        __syncthreads();
    }

    if (OUT_F32) {
        float* C = (float*)Cout;
#pragma unroll
        for (int mi = 0; mi < 4; ++mi)
#pragma unroll
            for (int ni = 0; ni < 4; ++ni)
#pragma unroll
                for (int r = 0; r < 4; ++r)
                    C[(size_t)(m0 + wm * 64 + mi * 16 + quad * 4 + r) * N +
                      (n0 + wn * 64 + ni * 16 + l16)] = acc[mi][ni][r];
    } else {
        bf16* C = (bf16*)Cout;
#pragma unroll
        for (int mi = 0; mi < 4; ++mi)
#pragma unroll
            for (int ni = 0; ni < 4; ++ni)
#pragma unroll
                for (int r = 0; r < 4; ++r)
                    C[(size_t)(m0 + wm * 64 + mi * 16 + quad * 4 + r) * N +
                      (n0 + wn * 64 + ni * 16 + l16)] = (bf16)acc[mi][ni][r];
    }
}

// ---------------- flash attention (v4: split-K) ----------------
// grid: (S/128, B*H, 2); 256 threads = 4 waves, each wave owns 32 q-rows;
// z = key-half (1024 keys each). No-max softmax makes splits additive:
// block writes UNNORMALIZED o (fp32) and l partials; combine_att finishes.
// 1024 blocks = 4 blocks/CU (LDS 35.8 KB x4 = 143 < 160 KB).

__global__ __launch_bounds__(256, 4) void flash_attn(
    const bf16* __restrict__ QKV, const bf16* __restrict__ VT,
    float* __restrict__ op, float* __restrict__ lp) {
    constexpr int LDK = 72;
    constexpr int LDP = 68;
    __shared__ __attribute__((aligned(16))) bf16 Ks[64 * LDK];
    __shared__ __attribute__((aligned(16))) bf16 Vs[64 * LDK];
    __shared__ __attribute__((aligned(16))) bf16 Ps[128 * LDP];

    const int tid = threadIdx.x, wid = tid >> 6, lane = tid & 63;
    const int quad = lane >> 4, l16 = lane & 15;
    const int qt = blockIdx.x;
    const int bh = blockIdx.y;
    const int kh = blockIdx.z;   // key half
    const int b = bh >> 4, h = bh & 15;
    const int q0 = qt * 128;

    const int row8 = tid >> 3, col8 = (tid & 7) * 8;

    // ---- prologue: Q tile 128x64 -> Ps region, pull A-frags to registers ----
    {
        const bf16* qg = QKV + (size_t)(b * 2048 + q0 + row8) * 3072 + h * 64 + col8;
#pragma unroll
        for (int p = 0; p < 4; ++p)
            *(bf16x8*)&Ps[(p * 32 + row8) * LDP + col8] =
                *(const bf16x8*)(qg + (size_t)(p * 32) * 3072);
    }
    __syncthreads();
    bf16x8 qf[2][2];
#pragma unroll
    for (int mi = 0; mi < 2; ++mi)
#pragma unroll
        for (int ks = 0; ks < 2; ++ks)
            qf[mi][ks] = *(const bf16x8*)&Ps[(wid * 32 + mi * 16 + l16) * LDP + ks * 32 + quad * 8];

    const bf16* kg = QKV + (size_t)(b * 2048 + kh * 1024 + row8) * 3072 + 1024 + h * 64 + col8;
    const bf16* vg = VT + (size_t)(h * 64 + row8) * 4096 + b * 2048 + kh * 1024 + col8;

    // register double-buffer: preload tile 0
    bf16x8 kr0 = *(const bf16x8*)(kg);
    bf16x8 kr1 = *(const bf16x8*)(kg + (size_t)32 * 3072);
    bf16x8 vr0 = *(const bf16x8*)(vg);
    bf16x8 vr1 = *(const bf16x8*)(vg + (size_t)32 * 4096);

    f32x4 o[2][4];
    float lsum[2][4];
#pragma unroll
    for (int mi = 0; mi < 2; ++mi) {
#pragma unroll
        for (int ni = 0; ni < 4; ++ni) o[mi][ni] = (f32x4){0.f, 0.f, 0.f, 0.f};
#pragma unroll
        for (int r = 0; r < 4; ++r) lsum[mi][r] = 0.f;
    }

    for (int kc = 0; kc < 16; ++kc) {
        *(bf16x8*)&Ks[row8 * LDK + col8] = kr0;
        *(bf16x8*)&Ks[(row8 + 32) * LDK + col8] = kr1;
        *(bf16x8*)&Vs[row8 * LDK + col8] = vr0;
        *(bf16x8*)&Vs[(row8 + 32) * LDK + col8] = vr1;
        __syncthreads();

        if (kc < 15) {
            const size_t ko = (size_t)(kc + 1) * 64;
            kr0 = *(const bf16x8*)(kg + ko * 3072);
            kr1 = *(const bf16x8*)(kg + (ko + 32) * 3072);
            vr0 = *(const bf16x8*)(vg + ko);
            vr1 = *(const bf16x8*)(vg + (size_t)32 * 4096 + ko);
        }

        // ---- S = Q K^T : 32 q-rows x 64 keys per wave (16 MFMA) ----
        f32x4 s[2][4];
#pragma unroll
        for (int mi = 0; mi < 2; ++mi)
#pragma unroll
            for (int ni = 0; ni < 4; ++ni) s[mi][ni] = (f32x4){0.f, 0.f, 0.f, 0.f};
#pragma unroll
        for (int ni = 0; ni < 4; ++ni) {
            const bf16x8 kf0 = *(const bf16x8*)&Ks[(ni * 16 + l16) * LDK + quad * 8];
            const bf16x8 kf1 = *(const bf16x8*)&Ks[(ni * 16 + l16) * LDK + 32 + quad * 8];
#pragma unroll
            for (int mi = 0; mi < 2; ++mi) {
                s[mi][ni] = __builtin_amdgcn_mfma_f32_16x16x32_bf16(qf[mi][0], kf0, s[mi][ni], 0, 0, 0);
                s[mi][ni] = __builtin_amdgcn_mfma_f32_16x16x32_bf16(qf[mi][1], kf1, s[mi][ni], 0, 0, 0);
            }
        }

        // ---- P = exp2(S); accumulate l; P -> LDS ----
#pragma unroll
        for (int mi = 0; mi < 2; ++mi)
#pragma unroll
            for (int ni = 0; ni < 4; ++ni)
#pragma unroll
                for (int r = 0; r < 4; ++r) {
                    const float p = __builtin_amdgcn_exp2f(s[mi][ni][r]);
                    lsum[mi][r] += p;
                    Ps[(wid * 32 + mi * 16 + quad * 4 + r) * LDP + ni * 16 + l16] = (bf16)p;
                }

        // ---- O += P V (16 MFMA) ----
#pragma unroll
        for (int ks = 0; ks < 2; ++ks) {
            bf16x8 pf[2];
#pragma unroll
            for (int mi = 0; mi < 2; ++mi)
                pf[mi] = *(const bf16x8*)&Ps[(wid * 32 + mi * 16 + l16) * LDP + ks * 32 + quad * 8];
#pragma unroll
            for (int ni = 0; ni < 4; ++ni) {
                const bf16x8 vf = *(const bf16x8*)&Vs[(ni * 16 + l16) * LDK + ks * 32 + quad * 8];
#pragma unroll
                for (int mi = 0; mi < 2; ++mi)
                    o[mi][ni] = __builtin_amdgcn_mfma_f32_16x16x32_bf16(pf[mi], vf, o[mi][ni], 0, 0, 0);
            }
        }
        __syncthreads();
    }

    // ---- l row-sums across 16 column-lanes; store partials ----
#pragma unroll
    for (int off = 1; off < 16; off <<= 1)
#pragma unroll
        for (int mi = 0; mi < 2; ++mi)
#pragma unroll
            for (int r = 0; r < 4; ++r) lsum[mi][r] += __shfl_xor(lsum[mi][r], off);

    if (l16 == 0) {
#pragma unroll
        for (int mi = 0; mi < 2; ++mi)
#pragma unroll
            for (int r = 0; r < 4; ++r)
                lp[(size_t)kh * 4096 * 16 +
                   (size_t)(b * 2048 + q0 + wid * 32 + mi * 16 + quad * 4 + r) * 16 + h] = lsum[mi][r];
    }
#pragma unroll
    for (int mi = 0; mi < 2; ++mi)
#pragma unroll
        for (int ni = 0; ni < 4; ++ni)
#pragma unroll
            for (int r = 0; r < 4; ++r)
                op[(size_t)kh * 4096 * 1024 +
                   (size_t)(b * 2048 + q0 + wid * 32 + mi * 16 + quad * 4 + r) * 1024 +
                   (h * 64 + ni * 16 + l16)] = o[mi][ni][r];
}

// combine: att = (o0+o1) / (l0+l1), fp32 -> bf16
__global__ void combine_att(const float* __restrict__ op, const float* __restrict__ lp,
                            bf16* __restrict__ att) {
    const int idx = (blockIdx.x * 256 + threadIdx.x) * 4;
    const int q = idx >> 10, h = (idx & 1023) >> 6;
    const float4 a = *(const float4*)(op + idx);
    const float4 c = *(const float4*)(op + (size_t)4096 * 1024 + idx);
    const float l = lp[q * 16 + h] + lp[4096 * 16 + q * 16 + h];
    const float inv = 1.0f / l;
    bf16 r[4] = {(bf16)((a.x + c.x) * inv), (bf16)((a.y + c.y) * inv),
                 (bf16)((a.z + c.z) * inv), (bf16)((a.w + c.w) * inv)};
    *(uint2*)(att + idx) = *(const uint2*)r;
}

// ---------------- launch ----------------

extern "C" void kernel_launch(void* const* d_in, const int* in_sizes, int n_in,
                              void* d_out, int out_size, void* d_ws, size_t ws_size,
                              hipStream_t stream) {
    (void)in_sizes; (void)n_in; (void)out_size; (void)ws_size;
    const float* x  = (const float*)d_in[0];
    const float* Wq = (const float*)d_in[1];
    const float* Wk = (const float*)d_in[2];
    const float* Wv = (const float*)d_in[3];
    const float* Wo = (const float*)d_in[4];

    char* ws = (char*)d_ws;
    bf16* xb    = (bf16*)(ws);                             // 8 MB  [4096][1024]
    bf16* att   = xb;                                      // alias: xb dead after QKV GEMM
    bf16* WqkvT = (bf16*)(ws + (size_t)8  * 1024 * 1024);  // 6 MB [3072][1024]
    bf16* WoT   = (bf16*)(ws + (size_t)14 * 1024 * 1024);  // 2 MB [1024][1024]
    bf16* QKV   = (bf16*)(ws + (size_t)16 * 1024 * 1024);  // 24 MB [4096][3072]
    bf16* VT    = (bf16*)(ws + (size_t)40 * 1024 * 1024);  // 8 MB [1024][4096]
    float* op   = (float*)(ws + (size_t)48 * 1024 * 1024); // 32 MB [2][4096][1024] fp32
    float* lp   = (float*)(ws + (size_t)80 * 1024 * 1024); // 512 KB [2][4096][16] fp32
    // total ~80.5 MB

    const int n_x = 2 * 2048 * 1024;  // 4194304
    convert_x<<<n_x / (256 * 4), 256, 0, stream>>>(x, xb, n_x);

    // all 4 weight transposes; Wq pre-scaled by C^-0.5 * log2(e)
    transpose_cvt_all<<<dim3(32, 32, 4), 256, 0, stream>>>(Wq, Wk, Wv, Wo, WqkvT, WoT);

    // QKV = xb @ [Wq|Wk|Wv] : M=4096 N=3072 K=1024 (768 blocks = 3/CU)
    gemm_bt<false><<<dim3(3072 / 128, 4096 / 128), 256, 0, stream>>>(
        xb, WqkvT, QKV, 4096, 3072, 1024);

    // V slice -> VT [1024][4096]
    transpose_v<<<dim3(32, 128), 256, 0, stream>>>(QKV + 2048, VT);

    // attention partials (split-K=2): 1024 blocks = 4/CU
    flash_attn<<<dim3(16, 32, 2), 256, 0, stream>>>(QKV, VT, op, lp);

    // att = normalize(o partials)
    combine_att<<<4096, 256, 0, stream>>>(op, lp, att);

    // out = att @ Wo : M=4096 N=1024 K=1024, fp32 out
    gemm_bt<true><<<dim3(1024 / 128, 4096 / 128), 256, 0, stream>>>(
        att, WoT, (float*)d_out, 4096, 1024, 1024);
}

// Round 5
// 199.359 us; speedup vs baseline: 1.0285x; 1.0285x over previous
//
#include <hip/hip_runtime.h>
#include <hip/hip_bf16.h>
#include <stdint.h>
#include <stddef.h>

// B=2, S=2048, D=1024, H=16, C=64
typedef __bf16 bf16;
typedef __bf16 bf16x4 __attribute__((ext_vector_type(4)));
typedef __bf16 bf16x8 __attribute__((ext_vector_type(8)));
typedef float f32x4 __attribute__((ext_vector_type(4)));

#define DEV __device__ __forceinline__

// async global->LDS, 16B per lane; LDS dest is wave-uniform base + lane*16
DEV void async16(const bf16* g, bf16* l) {
    __builtin_amdgcn_global_load_lds(
        (const __attribute__((address_space(1))) void*)g,
        (__attribute__((address_space(3))) void*)l,
        16, 0, 0);
}

// ---------------- conversions ----------------

__global__ void convert_x(const float* __restrict__ in, bf16* __restrict__ out, int n) {
    int i = (blockIdx.x * blockDim.x + threadIdx.x) * 4;
    if (i >= n) return;
    const float4 v = *(const float4*)(in + i);
    bf16 o4[4] = {(bf16)v.x, (bf16)v.y, (bf16)v.z, (bf16)v.w};
    *(uint2*)(out + i) = *(const uint2*)o4;
}

// all four 1024x1024 weight transposes in one launch (z = which weight)
__global__ void transpose_cvt_all(const float* __restrict__ Wq, const float* __restrict__ Wk,
                                  const float* __restrict__ Wv, const float* __restrict__ Wo,
                                  bf16* __restrict__ WqkvT, bf16* __restrict__ WoT) {
    const float* src;
    bf16* dst;
    float scale = 1.0f;
    switch (blockIdx.z) {
        case 0: src = Wq; dst = WqkvT; scale = 0.125f * 1.4426950408889634f; break;
        case 1: src = Wk; dst = WqkvT + 1024 * 1024; break;
        case 2: src = Wv; dst = WqkvT + 2 * 1024 * 1024; break;
        default: src = Wo; dst = WoT; break;
    }
    __shared__ float t[32][33];
    const int c0 = blockIdx.x * 32, r0 = blockIdx.y * 32;
    const int tx = threadIdx.x & 31, ty = threadIdx.x >> 5;  // 32x8
#pragma unroll
    for (int i = 0; i < 32; i += 8)
        t[ty + i][tx] = src[(size_t)(r0 + ty + i) * 1024 + c0 + tx];
    __syncthreads();
#pragma unroll
    for (int i = 0; i < 32; i += 8)
        dst[(size_t)(c0 + ty + i) * 1024 + r0 + tx] = (bf16)(t[tx][ty + i] * scale);
}

// V slice of QKV [4096][3072] (cols 2048..3071) -> VT [1024][4096]
__global__ void transpose_v(const bf16* __restrict__ V, bf16* __restrict__ VT) {
    __shared__ bf16 t[32][33];
    const int c0 = blockIdx.x * 32, r0 = blockIdx.y * 32;
    const int tx = threadIdx.x & 31, ty = threadIdx.x >> 5;  // 32x8
#pragma unroll
    for (int i = 0; i < 32; i += 8)
        t[ty + i][tx] = V[(size_t)(r0 + ty + i) * 3072 + c0 + tx];
    __syncthreads();
#pragma unroll
    for (int i = 0; i < 32; i += 8)
        VT[(size_t)(c0 + ty + i) * 4096 + r0 + tx] = t[tx][ty + i];
}

// ---------------- GEMM: C[m][n] = sum_k A[m][k] * BT[n][k] ----------------
// 128x128 tile, BK=64 staged as two BK=32 panels, m97-style.

template <bool OUT_F32>
__global__ __launch_bounds__(256, 3) void gemm_bt(
    const bf16* __restrict__ A, const bf16* __restrict__ BT, void* __restrict__ Cout,
    int M, int N, int K) {
    __shared__ __attribute__((aligned(16))) bf16 As[2 * 128 * 32];
    __shared__ __attribute__((aligned(16))) bf16 Bs[2 * 128 * 32];
    const int tid = threadIdx.x;
    const int wid = tid >> 6;
    const int lane = tid & 63;
    const int quad = lane >> 4;
    const int l16 = lane & 15;
    const int wm = wid >> 1, wn = wid & 1;
    const int m0 = blockIdx.y * 128, n0 = blockIdx.x * 128;

    const int srow = wid * 32 + (lane >> 2);
    const int skcol = (lane & 3) * 8;
    const bf16* ag = A + (size_t)(m0 + srow) * K + skcol;
    const bf16* bg = BT + (size_t)(n0 + srow) * K + skcol;

    f32x4 acc[4][4];
#pragma unroll
    for (int i = 0; i < 4; ++i)
#pragma unroll
        for (int j = 0; j < 4; ++j) acc[i][j] = (f32x4){0.f, 0.f, 0.f, 0.f};

    for (int k0 = 0; k0 < K; k0 += 64) {
#pragma unroll
        for (int p = 0; p < 2; ++p) {
            async16(ag + k0 + p * 32, &As[p * 4096 + (wid * 32) * 32]);
            async16(ag + (size_t)16 * K + k0 + p * 32, &As[p * 4096 + (wid * 32 + 16) * 32]);
            async16(bg + k0 + p * 32, &Bs[p * 4096 + (wid * 32) * 32]);
            async16(bg + (size_t)16 * K + k0 + p * 32, &Bs[p * 4096 + (wid * 32 + 16) * 32]);
        }
        __syncthreads();

#pragma unroll
        for (int ks = 0; ks < 2; ++ks) {
            bf16x8 af[4], bfr[4];
#pragma unroll
            for (int mi = 0; mi < 4; ++mi)
                af[mi] = *(const bf16x8*)&As[ks * 4096 + (wm * 64 + mi * 16 + l16) * 32 + quad * 8];
#pragma unroll
            for (int ni = 0; ni < 4; ++ni)
                bfr[ni] = *(const bf16x8*)&Bs[ks * 4096 + (wn * 64 + ni * 16 + l16) * 32 + quad * 8];
#pragma unroll
            for (int mi = 0; mi < 4; ++mi)
#pragma unroll
                for (int ni = 0; ni < 4; ++ni)
                    acc[mi][ni] = __builtin_amdgcn_mfma_f32_16x16x32_bf16(
                        af[mi], bfr[ni], acc[mi][ni], 0, 0, 0);
        }
        __syncthreads();
    }

    if (OUT_F32) {
        float* C = (float*)Cout;
#pragma unroll
        for (int mi = 0; mi < 4; ++mi)
#pragma unroll
            for (int ni = 0; ni < 4; ++ni)
#pragma unroll
                for (int r = 0; r < 4; ++r)
                    C[(size_t)(m0 + wm * 64 + mi * 16 + quad * 4 + r) * N +
                      (n0 + wn * 64 + ni * 16 + l16)] = acc[mi][ni][r];
    } else {
        bf16* C = (bf16*)Cout;
#pragma unroll
        for (int mi = 0; mi < 4; ++mi)
#pragma unroll
            for (int ni = 0; ni < 4; ++ni)
#pragma unroll
                for (int r = 0; r < 4; ++r)
                    C[(size_t)(m0 + wm * 64 + mi * 16 + quad * 4 + r) * N +
                      (n0 + wn * 64 + ni * 16 + l16)] = (bf16)acc[mi][ni][r];
    }
}

// ---------------- flash attention (v5: register-resident, no LDS in loop) ----
// grid: (S/128, B*H) = 512 blocks x 256 threads; 2 blocks/CU (VGPR-capped).
// Each wave owns ALL 128 q-rows x a private 16-key slice per iteration:
//   - Q B-frags in registers (loaded once, 64 VGPRs)
//   - K A-frags / V B-frags gathered straight from global (L2-resident)
//   - S^T = mfma(K, Q): D-layout == A-layout of P for K=16 contraction
//   - PV via 16x16x32 mfma with k-slots 4..7 zero-padded (K=16 effective)
//   - no __syncthreads in the loop; epilogue: LDS tree-reduce O across the
//     4 waves' disjoint key partials (additive: no-max softmax), normalize,
//     write att bf16 directly (combine kernel eliminated).

__global__ __launch_bounds__(256, 2) void flash_attn(
    const bf16* __restrict__ QKV, const bf16* __restrict__ VT, bf16* __restrict__ att) {
    // epilogue-only LDS: two 32KB reduce regions + l reduction
    __shared__ float Osc[2][32 * 256];  // [region][slot(mi*4+ct)*256 + lane*4 + r]
    __shared__ float Lred[4][128];
    __shared__ float Linv[128];

    const int tid = threadIdx.x, wid = tid >> 6, lane = tid & 63;
    const int quad = lane >> 4, l16 = lane & 15;
    const int qt = blockIdx.x;   // 0..15
    const int bh = blockIdx.y;   // 0..31
    const int b = bh >> 4, h = bh & 15;
    const int q0 = qt * 128;

    // ---- Q B-frags: Q[q=mi*16+l16][c=ks*32+quad*8 ..+7], resident ----
    bf16x8 qf[8][2];
    {
        const bf16* qbase = QKV + (size_t)(b * 2048 + q0 + l16) * 3072 + h * 64 + quad * 8;
#pragma unroll
        for (int mi = 0; mi < 8; ++mi)
#pragma unroll
            for (int ks = 0; ks < 2; ++ks)
                qf[mi][ks] = *(const bf16x8*)(qbase + (size_t)mi * 16 * 3072 + ks * 32);
    }

    // K A-frag base: K[key=wid*16+l16][c=quad*8..]; per iter += kc*64 rows
    const bf16* kbase = QKV + (size_t)(b * 2048 + wid * 16 + l16) * 3072 + 1024 + h * 64 + quad * 8;
    // V B-frag base: VT[c=ct*16+l16][key=wid*16+quad*4..+3]; per iter += kc*64
    const bf16* vbase = VT + (size_t)(h * 64 + l16) * 4096 + b * 2048 + wid * 16 + quad * 4;

    f32x4 o[8][4];
#pragma unroll
    for (int mi = 0; mi < 8; ++mi)
#pragma unroll
        for (int ct = 0; ct < 4; ++ct) o[mi][ct] = (f32x4){0.f, 0.f, 0.f, 0.f};
    float lsum[8];
#pragma unroll
    for (int mi = 0; mi < 8; ++mi) lsum[mi] = 0.f;

    for (int kc = 0; kc < 32; ++kc) {
        const bf16* kp = kbase + (size_t)kc * 64 * 3072;
        const bf16x8 kf0 = *(const bf16x8*)(kp);
        const bf16x8 kf1 = *(const bf16x8*)(kp + 32);

        const bf16* vp = vbase + kc * 64;
        bf16x8 vf[4];
#pragma unroll
        for (int ct = 0; ct < 4; ++ct) {
            const bf16x4 t = *(const bf16x4*)(vp + (size_t)ct * 16 * 4096);
            vf[ct] = (bf16x8){t[0], t[1], t[2], t[3],
                              (bf16)0.f, (bf16)0.f, (bf16)0.f, (bf16)0.f};
        }

#pragma unroll
        for (int mi = 0; mi < 8; ++mi) {
            // S^T tile: D[key=quad*4+r][q=mi*16+l16]
            f32x4 s = (f32x4){0.f, 0.f, 0.f, 0.f};
            s = __builtin_amdgcn_mfma_f32_16x16x32_bf16(kf0, qf[mi][0], s, 0, 0, 0);
            s = __builtin_amdgcn_mfma_f32_16x16x32_bf16(kf1, qf[mi][1], s, 0, 0, 0);

            // P = exp2(S); lane holds P[q=mi*16+l16][key=quad*4+r] == A-frag slots
            const float p0 = __builtin_amdgcn_exp2f(s[0]);
            const float p1 = __builtin_amdgcn_exp2f(s[1]);
            const float p2 = __builtin_amdgcn_exp2f(s[2]);
            const float p3 = __builtin_amdgcn_exp2f(s[3]);
            lsum[mi] += (p0 + p1) + (p2 + p3);
            const bf16x8 pf = (bf16x8){(bf16)p0, (bf16)p1, (bf16)p2, (bf16)p3,
                                       (bf16)0.f, (bf16)0.f, (bf16)0.f, (bf16)0.f};
#pragma unroll
            for (int ct = 0; ct < 4; ++ct)
                o[mi][ct] = __builtin_amdgcn_mfma_f32_16x16x32_bf16(pf, vf[ct], o[mi][ct], 0, 0, 0);
        }
    }

    // ---- epilogue ----
    // l: reduce over quads (keys within wave), publish per-wave partials
#pragma unroll
    for (int mi = 0; mi < 8; ++mi) {
        lsum[mi] += __shfl_xor(lsum[mi], 16);
        lsum[mi] += __shfl_xor(lsum[mi], 32);
    }
    if (quad == 0) {
#pragma unroll
        for (int mi = 0; mi < 8; ++mi) Lred[wid][mi * 16 + l16] = lsum[mi];
    }
    // O: waves 2,3 publish full partials
    if (wid >= 2) {
        float* dst = &Osc[wid - 2][0];
#pragma unroll
        for (int mi = 0; mi < 8; ++mi)
#pragma unroll
            for (int ct = 0; ct < 4; ++ct)
                *(f32x4*)(dst + (mi * 4 + ct) * 256 + lane * 4) = o[mi][ct];
    }
    __syncthreads();

    if (tid < 128) {
        const float l = Lred[0][tid] + Lred[1][tid] + Lred[2][tid] + Lred[3][tid];
        Linv[tid] = 1.0f / l;
    }
    if (wid < 2) {
        const float* src = &Osc[wid][0];
#pragma unroll
        for (int mi = 0; mi < 8; ++mi)
#pragma unroll
            for (int ct = 0; ct < 4; ++ct)
                o[mi][ct] += *(const f32x4*)(src + (mi * 4 + ct) * 256 + lane * 4);
    }
    __syncthreads();

    if (wid == 1) {
        float* dst = &Osc[0][0];
#pragma unroll
        for (int mi = 0; mi < 8; ++mi)
#pragma unroll
            for (int ct = 0; ct < 4; ++ct)
                *(f32x4*)(dst + (mi * 4 + ct) * 256 + lane * 4) = o[mi][ct];
    }
    __syncthreads();

    if (wid == 0) {
        const float* src = &Osc[0][0];
#pragma unroll
        for (int mi = 0; mi < 8; ++mi)
#pragma unroll
            for (int ct = 0; ct < 4; ++ct)
                o[mi][ct] += *(const f32x4*)(src + (mi * 4 + ct) * 256 + lane * 4);
        // normalize + store: O[q=q0+mi*16+quad*4+r][h*64+ct*16+l16]
#pragma unroll
        for (int mi = 0; mi < 8; ++mi)
#pragma unroll
            for (int r = 0; r < 4; ++r) {
                const float inv = Linv[mi * 16 + quad * 4 + r];
                bf16* orow = att + (size_t)(b * 2048 + q0 + mi * 16 + quad * 4 + r) * 1024 + h * 64 + l16;
#pragma unroll
                for (int ct = 0; ct < 4; ++ct)
                    orow[ct * 16] = (bf16)(o[mi][ct][r] * inv);
            }
    }
}

// ---------------- launch ----------------

extern "C" void kernel_launch(void* const* d_in, const int* in_sizes, int n_in,
                              void* d_out, int out_size, void* d_ws, size_t ws_size,
                              hipStream_t stream) {
    (void)in_sizes; (void)n_in; (void)out_size; (void)ws_size;
    const float* x  = (const float*)d_in[0];
    const float* Wq = (const float*)d_in[1];
    const float* Wk = (const float*)d_in[2];
    const float* Wv = (const float*)d_in[3];
    const float* Wo = (const float*)d_in[4];

    char* ws = (char*)d_ws;
    bf16* xb    = (bf16*)(ws);                             // 8 MB  [4096][1024]
    bf16* att   = xb;                                      // alias: xb dead after QKV GEMM
    bf16* WqkvT = (bf16*)(ws + (size_t)8  * 1024 * 1024);  // 6 MB [3072][1024]
    bf16* WoT   = (bf16*)(ws + (size_t)14 * 1024 * 1024);  // 2 MB [1024][1024]
    bf16* QKV   = (bf16*)(ws + (size_t)16 * 1024 * 1024);  // 24 MB [4096][3072]
    bf16* VT    = (bf16*)(ws + (size_t)40 * 1024 * 1024);  // 8 MB [1024][4096]
    // total 48 MB

    const int n_x = 2 * 2048 * 1024;  // 4194304
    convert_x<<<n_x / (256 * 4), 256, 0, stream>>>(x, xb, n_x);

    // all 4 weight transposes; Wq pre-scaled by C^-0.5 * log2(e)
    transpose_cvt_all<<<dim3(32, 32, 4), 256, 0, stream>>>(Wq, Wk, Wv, Wo, WqkvT, WoT);

    // QKV = xb @ [Wq|Wk|Wv] : M=4096 N=3072 K=1024 (768 blocks = 3/CU)
    gemm_bt<false><<<dim3(3072 / 128, 4096 / 128), 256, 0, stream>>>(
        xb, WqkvT, QKV, 4096, 3072, 1024);

    // V slice -> VT [1024][4096]
    transpose_v<<<dim3(32, 128), 256, 0, stream>>>(QKV + 2048, VT);

    // attention -> att[bs][hc] (fully fused, writes normalized bf16)
    flash_attn<<<dim3(16, 32), 256, 0, stream>>>(QKV, VT, att);

    // out = att @ Wo : M=4096 N=1024 K=1024, fp32 out
    gemm_bt<true><<<dim3(1024 / 128, 4096 / 128), 256, 0, stream>>>(
        att, WoT, (float*)d_out, 4096, 1024, 1024);
}

// Round 6
// 188.180 us; speedup vs baseline: 1.0896x; 1.0594x over previous
//
#include <hip/hip_runtime.h>
#include <hip/hip_bf16.h>
#include <stdint.h>
#include <stddef.h>

// B=2, S=2048, D=1024, H=16, C=64
typedef __bf16 bf16;
typedef __bf16 bf16x4 __attribute__((ext_vector_type(4)));
typedef __bf16 bf16x8 __attribute__((ext_vector_type(8)));
typedef float f32x4 __attribute__((ext_vector_type(4)));

#define DEV __device__ __forceinline__

// async global->LDS, 16B per lane; LDS dest is wave-uniform base + lane*16
DEV void async16(const bf16* g, bf16* l) {
    __builtin_amdgcn_global_load_lds(
        (const __attribute__((address_space(1))) void*)g,
        (__attribute__((address_space(3))) void*)l,
        16, 0, 0);
}

// ---------------- conversions ----------------

__global__ void convert_x(const float* __restrict__ in, bf16* __restrict__ out, int n) {
    int i = (blockIdx.x * blockDim.x + threadIdx.x) * 4;
    if (i >= n) return;
    const float4 v = *(const float4*)(in + i);
    bf16 o4[4] = {(bf16)v.x, (bf16)v.y, (bf16)v.z, (bf16)v.w};
    *(uint2*)(out + i) = *(const uint2*)o4;
}

// all four 1024x1024 weight transposes in one launch (z = which weight)
__global__ void transpose_cvt_all(const float* __restrict__ Wq, const float* __restrict__ Wk,
                                  const float* __restrict__ Wv, const float* __restrict__ Wo,
                                  bf16* __restrict__ WqkvT, bf16* __restrict__ WoT) {
    const float* src;
    bf16* dst;
    float scale = 1.0f;
    switch (blockIdx.z) {
        case 0: src = Wq; dst = WqkvT; scale = 0.125f * 1.4426950408889634f; break;
        case 1: src = Wk; dst = WqkvT + 1024 * 1024; break;
        case 2: src = Wv; dst = WqkvT + 2 * 1024 * 1024; break;
        default: src = Wo; dst = WoT; break;
    }
    __shared__ float t[32][33];
    const int c0 = blockIdx.x * 32, r0 = blockIdx.y * 32;
    const int tx = threadIdx.x & 31, ty = threadIdx.x >> 5;  // 32x8
#pragma unroll
    for (int i = 0; i < 32; i += 8)
        t[ty + i][tx] = src[(size_t)(r0 + ty + i) * 1024 + c0 + tx];
    __syncthreads();
#pragma unroll
    for (int i = 0; i < 32; i += 8)
        dst[(size_t)(c0 + ty + i) * 1024 + r0 + tx] = (bf16)(t[tx][ty + i] * scale);
}

// V slice of QKV [4096][3072] (cols 2048..3071) -> VT [1024][4096]
__global__ void transpose_v(const bf16* __restrict__ V, bf16* __restrict__ VT) {
    __shared__ bf16 t[32][33];
    const int c0 = blockIdx.x * 32, r0 = blockIdx.y * 32;
    const int tx = threadIdx.x & 31, ty = threadIdx.x >> 5;  // 32x8
#pragma unroll
    for (int i = 0; i < 32; i += 8)
        t[ty + i][tx] = V[(size_t)(r0 + ty + i) * 3072 + c0 + tx];
    __syncthreads();
#pragma unroll
    for (int i = 0; i < 32; i += 8)
        VT[(size_t)(c0 + ty + i) * 4096 + r0 + tx] = t[tx][ty + i];
}

// ---------------- GEMM: C[m][n] = sum_k A[m][k] * BT[n][k] ----------------
// 128x128 tile, BK=64 staged as two BK=32 panels, m97-style.

template <bool OUT_F32>
__global__ __launch_bounds__(256, 3) void gemm_bt(
    const bf16* __restrict__ A, const bf16* __restrict__ BT, void* __restrict__ Cout,
    int M, int N, int K) {
    __shared__ __attribute__((aligned(16))) bf16 As[2 * 128 * 32];
    __shared__ __attribute__((aligned(16))) bf16 Bs[2 * 128 * 32];
    const int tid = threadIdx.x;
    const int wid = tid >> 6;
    const int lane = tid & 63;
    const int quad = lane >> 4;
    const int l16 = lane & 15;
    const int wm = wid >> 1, wn = wid & 1;
    const int m0 = blockIdx.y * 128, n0 = blockIdx.x * 128;

    const int srow = wid * 32 + (lane >> 2);
    const int skcol = (lane & 3) * 8;
    const bf16* ag = A + (size_t)(m0 + srow) * K + skcol;
    const bf16* bg = BT + (size_t)(n0 + srow) * K + skcol;

    f32x4 acc[4][4];
#pragma unroll
    for (int i = 0; i < 4; ++i)
#pragma unroll
        for (int j = 0; j < 4; ++j) acc[i][j] = (f32x4){0.f, 0.f, 0.f, 0.f};

    for (int k0 = 0; k0 < K; k0 += 64) {
#pragma unroll
        for (int p = 0; p < 2; ++p) {
            async16(ag + k0 + p * 32, &As[p * 4096 + (wid * 32) * 32]);
            async16(ag + (size_t)16 * K + k0 + p * 32, &As[p * 4096 + (wid * 32 + 16) * 32]);
            async16(bg + k0 + p * 32, &Bs[p * 4096 + (wid * 32) * 32]);
            async16(bg + (size_t)16 * K + k0 + p * 32, &Bs[p * 4096 + (wid * 32 + 16) * 32]);
        }
        __syncthreads();

#pragma unroll
        for (int ks = 0; ks < 2; ++ks) {
            bf16x8 af[4], bfr[4];
#pragma unroll
            for (int mi = 0; mi < 4; ++mi)
                af[mi] = *(const bf16x8*)&As[ks * 4096 + (wm * 64 + mi * 16 + l16) * 32 + quad * 8];
#pragma unroll
            for (int ni = 0; ni < 4; ++ni)
                bfr[ni] = *(const bf16x8*)&Bs[ks * 4096 + (wn * 64 + ni * 16 + l16) * 32 + quad * 8];
#pragma unroll
            for (int mi = 0; mi < 4; ++mi)
#pragma unroll
                for (int ni = 0; ni < 4; ++ni)
                    acc[mi][ni] = __builtin_amdgcn_mfma_f32_16x16x32_bf16(
                        af[mi], bfr[ni], acc[mi][ni], 0, 0, 0);
        }
        __syncthreads();
    }

    if (OUT_F32) {
        float* C = (float*)Cout;
#pragma unroll
        for (int mi = 0; mi < 4; ++mi)
#pragma unroll
            for (int ni = 0; ni < 4; ++ni)
#pragma unroll
                for (int r = 0; r < 4; ++r)
                    C[(size_t)(m0 + wm * 64 + mi * 16 + quad * 4 + r) * N +
                      (n0 + wn * 64 + ni * 16 + l16)] = acc[mi][ni][r];
    } else {
        bf16* C = (bf16*)Cout;
#pragma unroll
        for (int mi = 0; mi < 4; ++mi)
#pragma unroll
            for (int ni = 0; ni < 4; ++ni)
#pragma unroll
                for (int r = 0; r < 4; ++r)
                    C[(size_t)(m0 + wm * 64 + mi * 16 + quad * 4 + r) * N +
                      (n0 + wn * 64 + ni * 16 + l16)] = (bf16)acc[mi][ni][r];
    }
}

// ---------------- flash attention (v6) ----------------
// grid (S/128, B*H) = 512 blocks, 4 waves in 2x2 (q-half x key-half).
// Big-iter = 128 keys staged coalesced into padded LDS (register-prefetch
// double buffer); Q B-frags + P stay in registers (S^T trick); PV runs at
// full K=32 by pairing two 16-key groups into one MFMA (j0..3 / j4..7).
// No-max softmax (scores bounded, scale*log2e folded into Wq); epilogue:
// one-barrier cross-wave O reduce in LDS (aliased over staging buffer).

__global__ __launch_bounds__(256, 2) void flash_attn(
    const bf16* __restrict__ QKV, const bf16* __restrict__ VT, bf16* __restrict__ att) {
    constexpr int LDK = 72;   // Ks stride: frag-read banks 4*(l16+quad) uniform
    constexpr int LDV = 136;  // Vs stride: b64 reads 2-way (free), writes 8-phase
    __shared__ __attribute__((aligned(16))) char smem[36864];
    bf16* Ks = (bf16*)smem;                // [128][72]  = 18432 B
    bf16* Vs = (bf16*)(smem + 18432);      // [64][136]  = 17408 B -> 35840
    float* Osc = (float*)smem;             // epilogue alias: 2 regions x 16 KB
    float* Lred = (float*)(smem + 32768);  // [4][64] floats

    const int tid = threadIdx.x, wid = tid >> 6, lane = tid & 63;
    const int quad = lane >> 4, l16 = lane & 15;
    const int qh = wid >> 1, kh = wid & 1;
    const int qt = blockIdx.x, bh = blockIdx.y;
    const int b = bh >> 4, h = bh & 15;
    const int q0 = qt * 128;

    // ---- Q B-frags (resident): B[k=quad*8+j][n=l16] = Q[q][c] ----
    bf16x8 qf[4][2];
    {
        const bf16* qbase = QKV + (size_t)(b * 2048 + q0 + qh * 64 + l16) * 3072 + h * 64 + quad * 8;
#pragma unroll
        for (int mi = 0; mi < 4; ++mi)
#pragma unroll
            for (int ks = 0; ks < 2; ++ks)
                qf[mi][ks] = *(const bf16x8*)(qbase + (size_t)mi * 16 * 3072 + ks * 32);
    }

    // staging geometry (coalesced): K 128 rows x 128 B, V 64 rows x 256 B
    const int krow = tid >> 3, kcol = (tid & 7) * 8;   // 32 rows/pass, 4 passes
    const int vrow = tid >> 4, vcol = (tid & 15) * 8;  // 16 rows/pass, 4 passes
    const bf16* kg = QKV + (size_t)(b * 2048 + krow) * 3072 + 1024 + h * 64 + kcol;
    const bf16* vg = VT + (size_t)(h * 64 + vrow) * 4096 + b * 2048 + vcol;

    bf16x8 kr[4], vr[4];
#pragma unroll
    for (int p = 0; p < 4; ++p) {
        kr[p] = *(const bf16x8*)(kg + (size_t)(32 * p) * 3072);
        vr[p] = *(const bf16x8*)(vg + (size_t)(16 * p) * 4096);
    }

    f32x4 o[4][4];
    float lsum[4];
#pragma unroll
    for (int mi = 0; mi < 4; ++mi) {
        lsum[mi] = 0.f;
#pragma unroll
        for (int ct = 0; ct < 4; ++ct) o[mi][ct] = (f32x4){0.f, 0.f, 0.f, 0.f};
    }

    for (int it = 0; it < 16; ++it) {
        // ---- stage prefetched regs -> LDS ----
#pragma unroll
        for (int p = 0; p < 4; ++p) {
            *(bf16x8*)&Ks[(32 * p + krow) * LDK + kcol] = kr[p];
            *(bf16x8*)&Vs[(16 * p + vrow) * LDV + vcol] = vr[p];
        }
        __syncthreads();

        // ---- prefetch next big-iter (hidden behind compute) ----
        if (it < 15) {
            const size_t ko = (size_t)(it + 1) * 128;
#pragma unroll
            for (int p = 0; p < 4; ++p) {
                kr[p] = *(const bf16x8*)(kg + (ko + 32 * p) * 3072);
                vr[p] = *(const bf16x8*)(vg + (size_t)(16 * p) * 4096 + ko);
            }
        }

        // ---- compute: wave's 64 keys as 2 pairs of 16-key groups ----
#pragma unroll
        for (int pr = 0; pr < 2; ++pr) {
            const int kb = kh * 64 + pr * 32;  // pair base (rel key)
            // K A-frags: A[m=l16 (key)][k=quad*8+j (c)]
            const bf16x8 kfA0 = *(const bf16x8*)&Ks[(kb + l16) * LDK + quad * 8];
            const bf16x8 kfA1 = *(const bf16x8*)&Ks[(kb + l16) * LDK + 32 + quad * 8];
            const bf16x8 kfB0 = *(const bf16x8*)&Ks[(kb + 16 + l16) * LDK + quad * 8];
            const bf16x8 kfB1 = *(const bf16x8*)&Ks[(kb + 16 + l16) * LDK + 32 + quad * 8];
            // V B-frags: B[k-slot(quad,j)][n=l16 (c)]; j0..3 -> keys kb+quad*4..,
            // j4..7 -> keys kb+16+quad*4..
            bf16x8 vf[4];
#pragma unroll
            for (int ct = 0; ct < 4; ++ct) {
                const bf16x4 lo = *(const bf16x4*)&Vs[(ct * 16 + l16) * LDV + kb + quad * 4];
                const bf16x4 hi = *(const bf16x4*)&Vs[(ct * 16 + l16) * LDV + kb + 16 + quad * 4];
                vf[ct] = (bf16x8){lo[0], lo[1], lo[2], lo[3], hi[0], hi[1], hi[2], hi[3]};
            }
#pragma unroll
            for (int mi = 0; mi < 4; ++mi) {
                // S^T tiles: D[key=quad*4+r][q=l16]
                f32x4 sA = (f32x4){0.f, 0.f, 0.f, 0.f};
                f32x4 sB = (f32x4){0.f, 0.f, 0.f, 0.f};
                sA = __builtin_amdgcn_mfma_f32_16x16x32_bf16(kfA0, qf[mi][0], sA, 0, 0, 0);
                sA = __builtin_amdgcn_mfma_f32_16x16x32_bf16(kfA1, qf[mi][1], sA, 0, 0, 0);
                sB = __builtin_amdgcn_mfma_f32_16x16x32_bf16(kfB0, qf[mi][0], sB, 0, 0, 0);
                sB = __builtin_amdgcn_mfma_f32_16x16x32_bf16(kfB1, qf[mi][1], sB, 0, 0, 0);

                const float pa0 = __builtin_amdgcn_exp2f(sA[0]);
                const float pa1 = __builtin_amdgcn_exp2f(sA[1]);
                const float pa2 = __builtin_amdgcn_exp2f(sA[2]);
                const float pa3 = __builtin_amdgcn_exp2f(sA[3]);
                const float pb0 = __builtin_amdgcn_exp2f(sB[0]);
                const float pb1 = __builtin_amdgcn_exp2f(sB[1]);
                const float pb2 = __builtin_amdgcn_exp2f(sB[2]);
                const float pb3 = __builtin_amdgcn_exp2f(sB[3]);
                lsum[mi] += ((pa0 + pa1) + (pa2 + pa3)) + ((pb0 + pb1) + (pb2 + pb3));
                // P A-frag: lane holds P[q=l16][key slots j0..7]
                const bf16x8 pf = (bf16x8){(bf16)pa0, (bf16)pa1, (bf16)pa2, (bf16)pa3,
                                           (bf16)pb0, (bf16)pb1, (bf16)pb2, (bf16)pb3};
#pragma unroll
                for (int ct = 0; ct < 4; ++ct)
                    o[mi][ct] = __builtin_amdgcn_mfma_f32_16x16x32_bf16(pf, vf[ct], o[mi][ct], 0, 0, 0);
            }
        }
        __syncthreads();
    }

    // ---- epilogue: l butterfly over quads, cross-wave O reduce (1 barrier) ----
#pragma unroll
    for (int mi = 0; mi < 4; ++mi) {
        lsum[mi] += __shfl_xor(lsum[mi], 16);
        lsum[mi] += __shfl_xor(lsum[mi], 32);
    }
    if (quad == 0) {
#pragma unroll
        for (int mi = 0; mi < 4; ++mi) Lred[wid * 64 + mi * 16 + l16] = lsum[mi];
    }
    if (kh == 1) {
        float* dst = Osc + qh * 4096;
#pragma unroll
        for (int mi = 0; mi < 4; ++mi)
#pragma unroll
            for (int ct = 0; ct < 4; ++ct)
                *(f32x4*)(dst + (mi * 4 + ct) * 256 + lane * 4) = o[mi][ct];
    }
    __syncthreads();

    if (kh == 0) {
        const float* src = Osc + qh * 4096;
#pragma unroll
        for (int mi = 0; mi < 4; ++mi)
#pragma unroll
            for (int ct = 0; ct < 4; ++ct)
                o[mi][ct] += *(const f32x4*)(src + (mi * 4 + ct) * 256 + lane * 4);
#pragma unroll
        for (int mi = 0; mi < 4; ++mi)
#pragma unroll
            for (int r = 0; r < 4; ++r) {
                const int qrow = mi * 16 + quad * 4 + r;
                const float l = Lred[(qh * 2) * 64 + qrow] + Lred[(qh * 2 + 1) * 64 + qrow];
                const float inv = 1.0f / l;
                bf16* orow = att + (size_t)(b * 2048 + q0 + qh * 64 + qrow) * 1024 + h * 64 + l16;
#pragma unroll
                for (int ct = 0; ct < 4; ++ct)
                    orow[ct * 16] = (bf16)(o[mi][ct][r] * inv);
            }
    }
}

// ---------------- launch ----------------

extern "C" void kernel_launch(void* const* d_in, const int* in_sizes, int n_in,
                              void* d_out, int out_size, void* d_ws, size_t ws_size,
                              hipStream_t stream) {
    (void)in_sizes; (void)n_in; (void)out_size; (void)ws_size;
    const float* x  = (const float*)d_in[0];
    const float* Wq = (const float*)d_in[1];
    const float* Wk = (const float*)d_in[2];
    const float* Wv = (const float*)d_in[3];
    const float* Wo = (const float*)d_in[4];

    char* ws = (char*)d_ws;
    bf16* xb    = (bf16*)(ws);                             // 8 MB  [4096][1024]
    bf16* att   = xb;                                      // alias: xb dead after QKV GEMM
    bf16* WqkvT = (bf16*)(ws + (size_t)8  * 1024 * 1024);  // 6 MB [3072][1024]
    bf16* WoT   = (bf16*)(ws + (size_t)14 * 1024 * 1024);  // 2 MB [1024][1024]
    bf16* QKV   = (bf16*)(ws + (size_t)16 * 1024 * 1024);  // 24 MB [4096][3072]
    bf16* VT    = (bf16*)(ws + (size_t)40 * 1024 * 1024);  // 8 MB [1024][4096]
    // total 48 MB

    const int n_x = 2 * 2048 * 1024;  // 4194304
    convert_x<<<n_x / (256 * 4), 256, 0, stream>>>(x, xb, n_x);

    // all 4 weight transposes; Wq pre-scaled by C^-0.5 * log2(e)
    transpose_cvt_all<<<dim3(32, 32, 4), 256, 0, stream>>>(Wq, Wk, Wv, Wo, WqkvT, WoT);

    // QKV = xb @ [Wq|Wk|Wv] : M=4096 N=3072 K=1024 (768 blocks = 3/CU)
    gemm_bt<false><<<dim3(3072 / 128, 4096 / 128), 256, 0, stream>>>(
        xb, WqkvT, QKV, 4096, 3072, 1024);

    // V slice -> VT [1024][4096]
    transpose_v<<<dim3(32, 128), 256, 0, stream>>>(QKV + 2048, VT);

    // attention -> att[bs][hc] (fused, writes normalized bf16)
    flash_attn<<<dim3(16, 32), 256, 0, stream>>>(QKV, VT, att);

    // out = att @ Wo : M=4096 N=1024 K=1024, fp32 out
    gemm_bt<true><<<dim3(1024 / 128, 4096 / 128), 256, 0, stream>>>(
        att, WoT, (float*)d_out, 4096, 1024, 1024);
}